// Round 14
// baseline (245.077 us; speedup 1.0000x reference)
//
#include <hip/hip_runtime.h>

typedef unsigned short u16;
typedef __attribute__((ext_vector_type(4))) float f32x4;
typedef __attribute__((ext_vector_type(16))) float f32x16;
typedef __attribute__((ext_vector_type(8))) short bf16x8;
typedef __attribute__((ext_vector_type(4))) unsigned short u16x4;
typedef __attribute__((ext_vector_type(4))) unsigned u32x4;
typedef __attribute__((ext_vector_type(2))) unsigned uv2;

__device__ __forceinline__ u16 f2bf(float f) {
  unsigned u = __float_as_uint(f);
  u += 0x7FFFu + ((u >> 16) & 1u);
  return (u16)(u >> 16);
}
__device__ __forceinline__ float bf2f(u16 v) {
  return __uint_as_float(((unsigned)v) << 16);
}

__device__ __forceinline__ void gload_lds16(const u16* g, u16* l) {
  __builtin_amdgcn_global_load_lds((const __attribute__((address_space(1))) void*)g,
                                   (__attribute__((address_space(3))) void*)l, 16, 0, 0);
}

__device__ __forceinline__ unsigned cvt_pk_bf16(float lo, float hi) {
  unsigned r;
  asm("v_cvt_pk_bf16_f32 %0, %1, %2" : "=v"(r) : "v"(lo), "v"(hi));
  return r;
}

__device__ __forceinline__ float fexp2(float x) {
#if __has_builtin(__builtin_amdgcn_exp2f)
  return __builtin_amdgcn_exp2f(x);
#else
  return __expf(x * 0.6931471805599453f);
#endif
}

// ---------------- fused prep: x->bf16 + wq/wk/wv/wo transposes ----------------
__global__ __launch_bounds__(256) void prep_fused(const float* __restrict__ x,
                                                  const float* __restrict__ wq,
                                                  const float* __restrict__ wk,
                                                  const float* __restrict__ wv,
                                                  const float* __restrict__ wo,
                                                  u16* __restrict__ xb,
                                                  u16* __restrict__ wqkvT,
                                                  u16* __restrict__ woT) {
  const int b = blockIdx.x, tid = threadIdx.x;
  if (b < 2048) {
    int i = (b * 256 + tid) * 8;
    float4 v0 = *(const float4*)&x[i];
    float4 v1 = *(const float4*)&x[i + 4];
    u16x4 o0 = {f2bf(v0.x), f2bf(v0.y), f2bf(v0.z), f2bf(v0.w)};
    u16x4 o1 = {f2bf(v1.x), f2bf(v1.y), f2bf(v1.z), f2bf(v1.w)};
    *(u16x4*)&xb[i] = o0;
    *(u16x4*)&xb[i + 4] = o1;
    return;
  }
  __shared__ float tile[32][33];
  int tb = b - 2048;
  const float* src;
  u16* dst;
  int C, nbase, r0, c0;
  if (tb < 4096) {
    src = wq; dst = wqkvT; C = 2048;
    c0 = (tb >> 6) * 32; r0 = (tb & 63) * 32; nbase = c0;
  } else if (tb < 4608) {
    tb -= 4096; src = wk; dst = wqkvT; C = 256;
    c0 = (tb >> 6) * 32; r0 = (tb & 63) * 32; nbase = 2048 + c0;
  } else if (tb < 5120) {
    tb -= 4608; src = wv; dst = wqkvT; C = 256;
    c0 = (tb >> 6) * 32; r0 = (tb & 63) * 32; nbase = 2304 + c0;
  } else {
    tb -= 5120; src = wo; dst = woT; C = 2048;
    c0 = (tb >> 6) * 32; r0 = (tb & 63) * 32; nbase = c0;
  }
  {
    int tr = tid >> 3, tc4 = (tid & 7) << 2;
    float4 v = *(const float4*)&src[(size_t)(r0 + tr) * C + c0 + tc4];
    tile[tr][tc4 + 0] = v.x;
    tile[tr][tc4 + 1] = v.y;
    tile[tr][tc4 + 2] = v.z;
    tile[tr][tc4 + 3] = v.w;
  }
  __syncthreads();
  {
    int orow = tid >> 3, oc = (tid & 7) << 2;
    u16x4 o;
#pragma unroll
    for (int e = 0; e < 4; ++e) o[e] = f2bf(tile[oc + e][orow]);
    *(u16x4*)&dst[(size_t)(nbase + orow) * 2048 + r0 + oc] = o;
  }
}

// ---------------- GEMM v5 (unchanged): 64x128 tile, 8 waves, BK=64, 1 barrier/iter ----------------
template <bool F32OUT, bool DO_ROPE>
__global__ __launch_bounds__(512, 6) void gemm_bt(const u16* __restrict__ A,
                                                  const u16* __restrict__ BT,
                                                  void* __restrict__ Cout,
                                                  int M, int N, int K,
                                                  const float* __restrict__ cosT,
                                                  const float* __restrict__ sinT,
                                                  u16* __restrict__ VTout) {
  const int bn = blockIdx.x * 128, bm = blockIdx.y * 64;
  const int tid = threadIdx.x;
  const int wid = tid >> 6, lane = tid & 63;
  const int wr = wid >> 2, wc = wid & 3;
  const int lrow = lane & 15, g = lane >> 4;

  __shared__ __align__(16) u16 As[2][64 * 64];
  __shared__ __align__(16) u16 Bs[2][128 * 64];

  const int srow = tid >> 3;
  const int cswz = (((tid & 7) ^ (srow & 7)) << 3);
  const u16* a_src = A + (size_t)(bm + srow) * K + cswz;
  const u16* b_src = BT + (size_t)(bn + srow) * K + cswz;

  const int swz16 = (lrow & 7) << 3;
  const int colsw0 = (g * 8) ^ swz16;
  const int colsw1 = (32 + g * 8) ^ swz16;

#define STAGE(buf, k0)                                                        \
  do {                                                                        \
    gload_lds16(a_src + (k0), &As[buf][0] + tid * 8);                         \
    gload_lds16(b_src + (k0), &Bs[buf][0] + tid * 8);                         \
    gload_lds16(b_src + (size_t)64 * K + (k0), &Bs[buf][0] + 4096 + tid * 8); \
  } while (0)

  f32x4 acc[2][2] = {};

  const int nt = K >> 6;
  STAGE(0, 0);
  int cur = 0;
  for (int t = 0; t < nt; ++t) {
    asm volatile("s_waitcnt vmcnt(0)" ::: "memory");
    __builtin_amdgcn_s_barrier();
    asm volatile("" ::: "memory");
    if (t + 1 < nt) STAGE(cur ^ 1, (t + 1) * 64);

    bf16x8 af[2][2], bfr[2][2];
#pragma unroll
    for (int m = 0; m < 2; ++m) {
      int row = wr * 32 + m * 16 + lrow;
      af[m][0] = *(const bf16x8*)&As[cur][row * 64 + colsw0];
      af[m][1] = *(const bf16x8*)&As[cur][row * 64 + colsw1];
    }
#pragma unroll
    for (int n = 0; n < 2; ++n) {
      int row = wc * 32 + n * 16 + lrow;
      bfr[n][0] = *(const bf16x8*)&Bs[cur][row * 64 + colsw0];
      bfr[n][1] = *(const bf16x8*)&Bs[cur][row * 64 + colsw1];
    }
#pragma unroll
    for (int ks = 0; ks < 2; ++ks)
#pragma unroll
      for (int m = 0; m < 2; ++m)
#pragma unroll
        for (int n = 0; n < 2; ++n)
          acc[m][n] =
              __builtin_amdgcn_mfma_f32_16x16x32_bf16(af[m][ks], bfr[n][ks], acc[m][n], 0, 0, 0);

    asm volatile("" ::: "memory");
    cur ^= 1;
  }
#undef STAGE

#pragma unroll
  for (int m = 0; m < 2; ++m) {
    int row0 = bm + wr * 32 + m * 16 + (g << 2);
#pragma unroll
    for (int n = 0; n < 2; ++n) {
      int col = bn + wc * 32 + n * 16 + lrow;
      f32x4 v = acc[m][n];
      if constexpr (DO_ROPE) {
        if (bn < 2304) {
          int i = (col & 63) >> 1;
          float sg = (col & 1) ? 1.f : -1.f;
#pragma unroll
          for (int r = 0; r < 4; ++r) {
            float pv = __shfl_xor(v[r], 1, 64);
            float c = cosT[(row0 + r) * 32 + i];
            float s = sinT[(row0 + r) * 32 + i];
            v[r] = v[r] * c + pv * s * sg;
          }
        } else {
          u16x4 o;
#pragma unroll
          for (int r = 0; r < 4; ++r) o[r] = f2bf(v[r]);
          *(u16x4*)&VTout[(size_t)(col - 2304) * 2048 + row0] = o;
          continue;
        }
      }
#pragma unroll
      for (int r = 0; r < 4; ++r) {
        if constexpr (F32OUT)
          ((float*)Cout)[(size_t)(row0 + r) * N + col] = v[r];
        else
          ((u16*)Cout)[(size_t)(row0 + r) * N + col] = f2bf(v[r]);
      }
    }
  }
}

// ---------------- flash attention v10: K dbuf + V single-buffer (48KB -> 3 blocks/CU) ----------------
// iter t: vmcnt(0) -> barrier -> stage V(t) [PV(t-1) reads done pre-barrier]
// -> stage K(t+1) -> QK(t) -> softmax -> vmcnt(2) [V landed, K in flight] -> PV(t).
__global__ __launch_bounds__(512, 6) void attn_kernel(const u16* __restrict__ QKV,
                                                      const u16* __restrict__ VT,
                                                      u16* __restrict__ attn_out) {
  const int h = blockIdx.x;
  const int yy = (int)blockIdx.y;
  const int qb = (yy < 8) ? yy : 23 - yy;
  const int tid = threadIdx.x, w = tid >> 6, lane = tid & 63;
  const int wq4 = w & 3, half = w >> 2;
  const int l31 = lane & 31, hh = lane >> 5;
  const int kh = h >> 3;
  const int q0w = qb * 128 + wq4 * 32;
  const int qg = q0w + l31;

  __shared__ __align__(16) u16 smem[24576];  // 48KB: K[2half][2buf][4096] + V[2half][4096]

  const int srow8 = lane >> 3;
  const int scol = (((lane & 7) ^ srow8) << 3);

#define KSTAGE(buf, kb)                                                              \
  do {                                                                               \
    u16* kd = smem + (half * 2 + (buf)) * 4096 + (wq4 * 8) * 64 + lane * 8;          \
    _Pragma("unroll") for (int p = 0; p < 2; ++p) {                                  \
      int rr = p * 32 + wq4 * 8 + srow8;                                             \
      gload_lds16(QKV + (size_t)((kb) + rr) * 2560 + 2048 + kh * 64 + scol,          \
                  kd + p * 2048);                                                    \
    }                                                                                \
  } while (0)

#define VSTAGE(kb)                                                                   \
  do {                                                                               \
    u16* vd = smem + 16384 + half * 4096 + (wq4 * 8) * 64 + lane * 8;                \
    _Pragma("unroll") for (int p = 0; p < 2; ++p) {                                  \
      int rr = p * 32 + wq4 * 8 + srow8;                                             \
      gload_lds16(VT + (size_t)(kh * 64 + rr) * 2048 + (kb) + scol, vd + p * 2048);  \
    }                                                                                \
  } while (0)

  bf16x8 qf[4];
  {
    size_t base = (size_t)qg * 2560 + h * 64 + hh * 8;
#pragma unroll
    for (int ks = 0; ks < 4; ++ks) qf[ks] = *(const bf16x8*)&QKV[base + ks * 16];
  }

  const int ksw = (l31 & 7) << 3;

  f32x16 acc0 = {}, acc1 = {};
  float mrun = -1e30f, lrun = 0.f;
  const float SC = 0.125f * 1.44269504088896f;

  const int NT = qb + 1;
  KSTAGE(0, half * 64);
  int cur = 0;

  for (int t = 0; t < NT; ++t) {
    const int kb = (2 * t + half) * 64;
    asm volatile("s_waitcnt vmcnt(0)" ::: "memory");
    __builtin_amdgcn_s_barrier();
    asm volatile("" ::: "memory");
    VSTAGE(kb);                               // V(t): used after QK+softmax below
    if (t + 1 < NT) KSTAGE(cur ^ 1, kb + 128);

    if (kb <= q0w + 31) {
      const u16* Kc = smem + (half * 2 + cur) * 4096;
      const u16* Vc = smem + 16384 + half * 4096;

      f32x16 sc0 = {}, sc1 = {};
      __builtin_amdgcn_s_setprio(1);
#pragma unroll
      for (int ks = 0; ks < 4; ++ks) {
        int c = (ks * 16 + hh * 8) ^ ksw;
        bf16x8 kf0 = *(const bf16x8*)&Kc[l31 * 64 + c];
        bf16x8 kf1 = *(const bf16x8*)&Kc[(32 + l31) * 64 + c];
        sc0 = __builtin_amdgcn_mfma_f32_32x32x16_bf16(kf0, qf[ks], sc0, 0, 0, 0);
        sc1 = __builtin_amdgcn_mfma_f32_32x32x16_bf16(kf1, qf[ks], sc1, 0, 0, 0);
      }
      __builtin_amdgcn_s_setprio(0);

      if (kb + 63 > q0w) {
#pragma unroll
        for (int r = 0; r < 16; ++r) {
          int keyoff = (r & 3) + 8 * (r >> 2) + 4 * hh;
          if (kb + keyoff > qg) sc0[r] = -1e5f;
          if (kb + 32 + keyoff > qg) sc1[r] = -1e5f;
        }
      }

      float m8[8];
#pragma unroll
      for (int i = 0; i < 8; ++i)
        m8[i] = fmaxf(fmaxf(sc0[i], sc0[i + 8]), fmaxf(sc1[i], sc1[i + 8]));
#pragma unroll
      for (int st = 4; st >= 1; st >>= 1)
#pragma unroll
        for (int i = 0; i < st; ++i) m8[i] = fmaxf(m8[i], m8[i + st]);
      float mx = fmaxf(m8[0], __shfl_xor(m8[0], 32, 64));
      float mxs = mx * SC;

      if (__any(mxs > mrun + 8.f)) {
        float nm = fmaxf(mrun, mxs);
        float fs = fexp2(mrun - nm);
        mrun = nm;
        lrun *= fs;
#pragma unroll
        for (int i = 0; i < 16; ++i) { acc0[i] *= fs; acc1[i] *= fs; }
      }

      float p0[16], p1[16];
      const float nmn = -mrun;
#pragma unroll
      for (int i = 0; i < 16; ++i) {
        p0[i] = fexp2(__builtin_fmaf(sc0[i], SC, nmn));
        p1[i] = fexp2(__builtin_fmaf(sc1[i], SC, nmn));
      }
      float s8[8];
#pragma unroll
      for (int i = 0; i < 8; ++i) s8[i] = (p0[i] + p0[i + 8]) + (p1[i] + p1[i + 8]);
#pragma unroll
      for (int st = 4; st >= 1; st >>= 1)
#pragma unroll
        for (int i = 0; i < st; ++i) s8[i] += s8[i + st];
      lrun += s8[0] + __shfl_xor(s8[0], 32, 64);

      bf16x8 pf[4];
#pragma unroll
      for (int tt = 0; tt < 2; ++tt) {
        const float* pp = tt ? p1 : p0;
        unsigned wd[8];
#pragma unroll
        for (int j = 0; j < 8; ++j) wd[j] = cvt_pk_bf16(pp[2 * j], pp[2 * j + 1]);
        uv2 sA = __builtin_amdgcn_permlane32_swap(wd[0], wd[2], false, false);
        uv2 sB = __builtin_amdgcn_permlane32_swap(wd[1], wd[3], false, false);
        uv2 sC = __builtin_amdgcn_permlane32_swap(wd[4], wd[6], false, false);
        uv2 sD = __builtin_amdgcn_permlane32_swap(wd[5], wd[7], false, false);
        u32x4 f0 = {sA[0], sB[0], sA[1], sB[1]};
        u32x4 f1 = {sC[0], sD[0], sC[1], sD[1]};
        pf[tt * 2 + 0] = __builtin_bit_cast(bf16x8, f0);
        pf[tt * 2 + 1] = __builtin_bit_cast(bf16x8, f1);
      }

      // V(t) must have landed; K(t+1)'s 2 loads may stay in flight
      if (t + 1 < NT)
        asm volatile("s_waitcnt vmcnt(2)" ::: "memory");
      else
        asm volatile("s_waitcnt vmcnt(0)" ::: "memory");

      __builtin_amdgcn_s_setprio(1);
#pragma unroll
      for (int ks = 0; ks < 4; ++ks) {
        int c = (ks * 16 + hh * 8) ^ ksw;
        bf16x8 vf0 = *(const bf16x8*)&Vc[l31 * 64 + c];
        bf16x8 vf1 = *(const bf16x8*)&Vc[(32 + l31) * 64 + c];
        acc0 = __builtin_amdgcn_mfma_f32_32x32x16_bf16(vf0, pf[ks], acc0, 0, 0, 0);
        acc1 = __builtin_amdgcn_mfma_f32_32x32x16_bf16(vf1, pf[ks], acc1, 0, 0, 0);
      }
      __builtin_amdgcn_s_setprio(0);
    }

    asm volatile("" ::: "memory");
    cur ^= 1;
  }
#undef KSTAGE
#undef VSTAGE

  __syncthreads();  // all compute reads of smem done before merge reuse

  float* MRG = (float*)smem;
  float4* CH = (float4*)smem;
  if (half == 1) {
#pragma unroll
    for (int c = 0; c < 4; ++c) {
      float4 v0 = {acc0[4 * c + 0], acc0[4 * c + 1], acc0[4 * c + 2], acc0[4 * c + 3]};
      float4 v1 = {acc1[4 * c + 0], acc1[4 * c + 1], acc1[4 * c + 2], acc1[4 * c + 3]};
      CH[(wq4 * 8 + c) * 64 + lane] = v0;
      CH[(wq4 * 8 + 4 + c) * 64 + lane] = v1;
    }
    MRG[8192 + wq4 * 128 + lane * 2 + 0] = mrun;
    MRG[8192 + wq4 * 128 + lane * 2 + 1] = lrun;
  }
  __syncthreads();
  if (half == 0) {
    float m1 = MRG[8192 + wq4 * 128 + lane * 2 + 0];
    float l1 = MRG[8192 + wq4 * 128 + lane * 2 + 1];
    float m = fmaxf(mrun, m1);
    float f0 = fexp2(mrun - m), f1 = fexp2(m1 - m);
    float inv = 1.f / (lrun * f0 + l1 * f1);
    float a = f0 * inv, b = f1 * inv;
    size_t obase = (size_t)qg * 2048 + h * 64;
#pragma unroll
    for (int c = 0; c < 4; ++c) {
      float4 r0 = CH[(wq4 * 8 + c) * 64 + lane];
      float4 r1 = CH[(wq4 * 8 + 4 + c) * 64 + lane];
      u16x4 o0, o1;
      o0[0] = f2bf(acc0[4 * c + 0] * a + r0.x * b);
      o0[1] = f2bf(acc0[4 * c + 1] * a + r0.y * b);
      o0[2] = f2bf(acc0[4 * c + 2] * a + r0.z * b);
      o0[3] = f2bf(acc0[4 * c + 3] * a + r0.w * b);
      o1[0] = f2bf(acc1[4 * c + 0] * a + r1.x * b);
      o1[1] = f2bf(acc1[4 * c + 1] * a + r1.y * b);
      o1[2] = f2bf(acc1[4 * c + 2] * a + r1.z * b);
      o1[3] = f2bf(acc1[4 * c + 3] * a + r1.w * b);
      *(u16x4*)&attn_out[obase + 8 * c + 4 * hh] = o0;
      *(u16x4*)&attn_out[obase + 32 + 8 * c + 4 * hh] = o1;
    }
  }
}

extern "C" void kernel_launch(void* const* d_in, const int* in_sizes, int n_in,
                              void* d_out, int out_size, void* d_ws, size_t ws_size,
                              hipStream_t stream) {
  const float* x = (const float*)d_in[0];
  const float* fcos = (const float*)d_in[1];
  const float* fsin = (const float*)d_in[2];
  const float* wq = (const float*)d_in[4];
  const float* wk = (const float*)d_in[5];
  const float* wv = (const float*)d_in[6];
  const float* wo = (const float*)d_in[7];

  char* ws = (char*)d_ws;
  u16* xb    = (u16*)(ws);                    // 8 MB (reused as attn later)
  u16* wqkvT = (u16*)(ws + (8u << 20));       // 10 MB
  u16* woT   = (u16*)(ws + (18u << 20));      // 8 MB
  u16* QKV   = (u16*)(ws + (26u << 20));      // 10 MB
  u16* VT    = (u16*)(ws + (36u << 20));      // 1 MB
  u16* attn  = xb;

  prep_fused<<<11264, 256, 0, stream>>>(x, wq, wk, wv, wo, xb, wqkvT, woT);

  gemm_bt<false, true><<<dim3(20, 32), 512, 0, stream>>>(xb, wqkvT, QKV, 2048, 2560, 2048,
                                                         fcos, fsin, VT);

  attn_kernel<<<dim3(32, 16), 512, 0, stream>>>(QKV, VT, attn);

  gemm_bt<true, false><<<dim3(16, 32), 512, 0, stream>>>(attn, woT, d_out, 2048, 2048, 2048,
                                                         nullptr, nullptr, nullptr);
}

// Round 15
// 114.775 us; speedup vs baseline: 2.1353x; 2.1353x over previous
//
#include <hip/hip_runtime.h>

typedef unsigned short u16;
typedef __attribute__((ext_vector_type(4))) float f32x4;
typedef __attribute__((ext_vector_type(16))) float f32x16;
typedef __attribute__((ext_vector_type(8))) short bf16x8;
typedef __attribute__((ext_vector_type(4))) unsigned short u16x4;
typedef __attribute__((ext_vector_type(4))) unsigned u32x4;
typedef __attribute__((ext_vector_type(2))) unsigned uv2;

__device__ __forceinline__ u16 f2bf(float f) {
  unsigned u = __float_as_uint(f);
  u += 0x7FFFu + ((u >> 16) & 1u);
  return (u16)(u >> 16);
}
__device__ __forceinline__ float bf2f(u16 v) {
  return __uint_as_float(((unsigned)v) << 16);
}

__device__ __forceinline__ void gload_lds16(const u16* g, u16* l) {
  __builtin_amdgcn_global_load_lds((const __attribute__((address_space(1))) void*)g,
                                   (__attribute__((address_space(3))) void*)l, 16, 0, 0);
}

__device__ __forceinline__ unsigned cvt_pk_bf16(float lo, float hi) {
  unsigned r;
  asm("v_cvt_pk_bf16_f32 %0, %1, %2" : "=v"(r) : "v"(lo), "v"(hi));
  return r;
}

__device__ __forceinline__ float fexp2(float x) {
#if __has_builtin(__builtin_amdgcn_exp2f)
  return __builtin_amdgcn_exp2f(x);
#else
  return __expf(x * 0.6931471805599453f);
#endif
}

// ---------------- fused prep: x->bf16 + wq/wk/wv/wo transposes ----------------
__global__ __launch_bounds__(256) void prep_fused(const float* __restrict__ x,
                                                  const float* __restrict__ wq,
                                                  const float* __restrict__ wk,
                                                  const float* __restrict__ wv,
                                                  const float* __restrict__ wo,
                                                  u16* __restrict__ xb,
                                                  u16* __restrict__ wqkvT,
                                                  u16* __restrict__ woT) {
  const int b = blockIdx.x, tid = threadIdx.x;
  if (b < 2048) {
    int i = (b * 256 + tid) * 8;
    float4 v0 = *(const float4*)&x[i];
    float4 v1 = *(const float4*)&x[i + 4];
    u16x4 o0 = {f2bf(v0.x), f2bf(v0.y), f2bf(v0.z), f2bf(v0.w)};
    u16x4 o1 = {f2bf(v1.x), f2bf(v1.y), f2bf(v1.z), f2bf(v1.w)};
    *(u16x4*)&xb[i] = o0;
    *(u16x4*)&xb[i + 4] = o1;
    return;
  }
  __shared__ float tile[32][33];
  int tb = b - 2048;
  const float* src;
  u16* dst;
  int C, nbase, r0, c0;
  if (tb < 4096) {
    src = wq; dst = wqkvT; C = 2048;
    c0 = (tb >> 6) * 32; r0 = (tb & 63) * 32; nbase = c0;
  } else if (tb < 4608) {
    tb -= 4096; src = wk; dst = wqkvT; C = 256;
    c0 = (tb >> 6) * 32; r0 = (tb & 63) * 32; nbase = 2048 + c0;
  } else if (tb < 5120) {
    tb -= 4608; src = wv; dst = wqkvT; C = 256;
    c0 = (tb >> 6) * 32; r0 = (tb & 63) * 32; nbase = 2304 + c0;
  } else {
    tb -= 5120; src = wo; dst = woT; C = 2048;
    c0 = (tb >> 6) * 32; r0 = (tb & 63) * 32; nbase = c0;
  }
  {
    int tr = tid >> 3, tc4 = (tid & 7) << 2;
    float4 v = *(const float4*)&src[(size_t)(r0 + tr) * C + c0 + tc4];
    tile[tr][tc4 + 0] = v.x;
    tile[tr][tc4 + 1] = v.y;
    tile[tr][tc4 + 2] = v.z;
    tile[tr][tc4 + 3] = v.w;
  }
  __syncthreads();
  {
    int orow = tid >> 3, oc = (tid & 7) << 2;
    u16x4 o;
#pragma unroll
    for (int e = 0; e < 4; ++e) o[e] = f2bf(tile[oc + e][orow]);
    *(u16x4*)&dst[(size_t)(nbase + orow) * 2048 + r0 + oc] = o;
  }
}

// ---------------- GEMM v5 (unchanged): 64x128 tile, 8 waves, BK=64, 1 barrier/iter ----------------
template <bool F32OUT, bool DO_ROPE>
__global__ __launch_bounds__(512, 6) void gemm_bt(const u16* __restrict__ A,
                                                  const u16* __restrict__ BT,
                                                  void* __restrict__ Cout,
                                                  int M, int N, int K,
                                                  const float* __restrict__ cosT,
                                                  const float* __restrict__ sinT,
                                                  u16* __restrict__ VTout) {
  const int bn = blockIdx.x * 128, bm = blockIdx.y * 64;
  const int tid = threadIdx.x;
  const int wid = tid >> 6, lane = tid & 63;
  const int wr = wid >> 2, wc = wid & 3;
  const int lrow = lane & 15, g = lane >> 4;

  __shared__ __align__(16) u16 As[2][64 * 64];
  __shared__ __align__(16) u16 Bs[2][128 * 64];

  const int srow = tid >> 3;
  const int cswz = (((tid & 7) ^ (srow & 7)) << 3);
  const u16* a_src = A + (size_t)(bm + srow) * K + cswz;
  const u16* b_src = BT + (size_t)(bn + srow) * K + cswz;

  const int swz16 = (lrow & 7) << 3;
  const int colsw0 = (g * 8) ^ swz16;
  const int colsw1 = (32 + g * 8) ^ swz16;

#define STAGE(buf, k0)                                                        \
  do {                                                                        \
    gload_lds16(a_src + (k0), &As[buf][0] + tid * 8);                         \
    gload_lds16(b_src + (k0), &Bs[buf][0] + tid * 8);                         \
    gload_lds16(b_src + (size_t)64 * K + (k0), &Bs[buf][0] + 4096 + tid * 8); \
  } while (0)

  f32x4 acc[2][2] = {};

  const int nt = K >> 6;
  STAGE(0, 0);
  int cur = 0;
  for (int t = 0; t < nt; ++t) {
    asm volatile("s_waitcnt vmcnt(0)" ::: "memory");
    __builtin_amdgcn_s_barrier();
    asm volatile("" ::: "memory");
    if (t + 1 < nt) STAGE(cur ^ 1, (t + 1) * 64);

    bf16x8 af[2][2], bfr[2][2];
#pragma unroll
    for (int m = 0; m < 2; ++m) {
      int row = wr * 32 + m * 16 + lrow;
      af[m][0] = *(const bf16x8*)&As[cur][row * 64 + colsw0];
      af[m][1] = *(const bf16x8*)&As[cur][row * 64 + colsw1];
    }
#pragma unroll
    for (int n = 0; n < 2; ++n) {
      int row = wc * 32 + n * 16 + lrow;
      bfr[n][0] = *(const bf16x8*)&Bs[cur][row * 64 + colsw0];
      bfr[n][1] = *(const bf16x8*)&Bs[cur][row * 64 + colsw1];
    }
#pragma unroll
    for (int ks = 0; ks < 2; ++ks)
#pragma unroll
      for (int m = 0; m < 2; ++m)
#pragma unroll
        for (int n = 0; n < 2; ++n)
          acc[m][n] =
              __builtin_amdgcn_mfma_f32_16x16x32_bf16(af[m][ks], bfr[n][ks], acc[m][n], 0, 0, 0);

    asm volatile("" ::: "memory");
    cur ^= 1;
  }
#undef STAGE

#pragma unroll
  for (int m = 0; m < 2; ++m) {
    int row0 = bm + wr * 32 + m * 16 + (g << 2);
#pragma unroll
    for (int n = 0; n < 2; ++n) {
      int col = bn + wc * 32 + n * 16 + lrow;
      f32x4 v = acc[m][n];
      if constexpr (DO_ROPE) {
        if (bn < 2304) {
          int i = (col & 63) >> 1;
          float sg = (col & 1) ? 1.f : -1.f;
#pragma unroll
          for (int r = 0; r < 4; ++r) {
            float pv = __shfl_xor(v[r], 1, 64);
            float c = cosT[(row0 + r) * 32 + i];
            float s = sinT[(row0 + r) * 32 + i];
            v[r] = v[r] * c + pv * s * sg;
          }
        } else {
          u16x4 o;
#pragma unroll
          for (int r = 0; r < 4; ++r) o[r] = f2bf(v[r]);
          *(u16x4*)&VTout[(size_t)(col - 2304) * 2048 + row0] = o;
          continue;
        }
      }
#pragma unroll
      for (int r = 0; r < 4; ++r) {
        if constexpr (F32OUT)
          ((float*)Cout)[(size_t)(row0 + r) * N + col] = v[r];
        else
          ((u16*)Cout)[(size_t)(row0 + r) * N + col] = f2bf(v[r]);
      }
    }
  }
}

// ---------------- flash attention v10b: v10 structure, NO min-waves clamp ----------------
// K dbuf + V single-buffer, 48KB LDS. Natural VGPR (~64-72) <= 85 still allows
// 6 waves/SIMD (3 blocks/CU); the (512,6) clamp caused 40-VGPR spill disaster.
__global__ __launch_bounds__(512) void attn_kernel(const u16* __restrict__ QKV,
                                                   const u16* __restrict__ VT,
                                                   u16* __restrict__ attn_out) {
  const int h = blockIdx.x;
  const int yy = (int)blockIdx.y;
  const int qb = (yy < 8) ? yy : 23 - yy;
  const int tid = threadIdx.x, w = tid >> 6, lane = tid & 63;
  const int wq4 = w & 3, half = w >> 2;
  const int l31 = lane & 31, hh = lane >> 5;
  const int kh = h >> 3;
  const int q0w = qb * 128 + wq4 * 32;
  const int qg = q0w + l31;

  __shared__ __align__(16) u16 smem[24576];  // 48KB: K[2half][2buf][4096] + V[2half][4096]

  const int srow8 = lane >> 3;
  const int scol = (((lane & 7) ^ srow8) << 3);

#define KSTAGE(buf, kb)                                                              \
  do {                                                                               \
    u16* kd = smem + (half * 2 + (buf)) * 4096 + (wq4 * 8) * 64 + lane * 8;          \
    _Pragma("unroll") for (int p = 0; p < 2; ++p) {                                  \
      int rr = p * 32 + wq4 * 8 + srow8;                                             \
      gload_lds16(QKV + (size_t)((kb) + rr) * 2560 + 2048 + kh * 64 + scol,          \
                  kd + p * 2048);                                                    \
    }                                                                                \
  } while (0)

#define VSTAGE(kb)                                                                   \
  do {                                                                               \
    u16* vd = smem + 16384 + half * 4096 + (wq4 * 8) * 64 + lane * 8;                \
    _Pragma("unroll") for (int p = 0; p < 2; ++p) {                                  \
      int rr = p * 32 + wq4 * 8 + srow8;                                             \
      gload_lds16(VT + (size_t)(kh * 64 + rr) * 2048 + (kb) + scol, vd + p * 2048);  \
    }                                                                                \
  } while (0)

  bf16x8 qf[4];
  {
    size_t base = (size_t)qg * 2560 + h * 64 + hh * 8;
#pragma unroll
    for (int ks = 0; ks < 4; ++ks) qf[ks] = *(const bf16x8*)&QKV[base + ks * 16];
  }

  const int ksw = (l31 & 7) << 3;

  f32x16 acc0 = {}, acc1 = {};
  float mrun = -1e30f, lrun = 0.f;
  const float SC = 0.125f * 1.44269504088896f;

  const int NT = qb + 1;
  KSTAGE(0, half * 64);
  int cur = 0;

  for (int t = 0; t < NT; ++t) {
    const int kb = (2 * t + half) * 64;
    asm volatile("s_waitcnt vmcnt(0)" ::: "memory");
    __builtin_amdgcn_s_barrier();
    asm volatile("" ::: "memory");
    VSTAGE(kb);                               // V(t): used after QK+softmax below
    if (t + 1 < NT) KSTAGE(cur ^ 1, kb + 128);

    if (kb <= q0w + 31) {
      const u16* Kc = smem + (half * 2 + cur) * 4096;
      const u16* Vc = smem + 16384 + half * 4096;

      f32x16 sc0 = {}, sc1 = {};
      __builtin_amdgcn_s_setprio(1);
#pragma unroll
      for (int ks = 0; ks < 4; ++ks) {
        int c = (ks * 16 + hh * 8) ^ ksw;
        bf16x8 kf0 = *(const bf16x8*)&Kc[l31 * 64 + c];
        bf16x8 kf1 = *(const bf16x8*)&Kc[(32 + l31) * 64 + c];
        sc0 = __builtin_amdgcn_mfma_f32_32x32x16_bf16(kf0, qf[ks], sc0, 0, 0, 0);
        sc1 = __builtin_amdgcn_mfma_f32_32x32x16_bf16(kf1, qf[ks], sc1, 0, 0, 0);
      }
      __builtin_amdgcn_s_setprio(0);

      if (kb + 63 > q0w) {
#pragma unroll
        for (int r = 0; r < 16; ++r) {
          int keyoff = (r & 3) + 8 * (r >> 2) + 4 * hh;
          if (kb + keyoff > qg) sc0[r] = -1e5f;
          if (kb + 32 + keyoff > qg) sc1[r] = -1e5f;
        }
      }

      float m8[8];
#pragma unroll
      for (int i = 0; i < 8; ++i)
        m8[i] = fmaxf(fmaxf(sc0[i], sc0[i + 8]), fmaxf(sc1[i], sc1[i + 8]));
#pragma unroll
      for (int st = 4; st >= 1; st >>= 1)
#pragma unroll
        for (int i = 0; i < st; ++i) m8[i] = fmaxf(m8[i], m8[i + st]);
      float mx = fmaxf(m8[0], __shfl_xor(m8[0], 32, 64));
      float mxs = mx * SC;

      if (__any(mxs > mrun + 8.f)) {
        float nm = fmaxf(mrun, mxs);
        float fs = fexp2(mrun - nm);
        mrun = nm;
        lrun *= fs;
#pragma unroll
        for (int i = 0; i < 16; ++i) { acc0[i] *= fs; acc1[i] *= fs; }
      }

      float p0[16], p1[16];
      const float nmn = -mrun;
#pragma unroll
      for (int i = 0; i < 16; ++i) {
        p0[i] = fexp2(__builtin_fmaf(sc0[i], SC, nmn));
        p1[i] = fexp2(__builtin_fmaf(sc1[i], SC, nmn));
      }
      float s8[8];
#pragma unroll
      for (int i = 0; i < 8; ++i) s8[i] = (p0[i] + p0[i + 8]) + (p1[i] + p1[i + 8]);
#pragma unroll
      for (int st = 4; st >= 1; st >>= 1)
#pragma unroll
        for (int i = 0; i < st; ++i) s8[i] += s8[i + st];
      lrun += s8[0] + __shfl_xor(s8[0], 32, 64);

      bf16x8 pf[4];
#pragma unroll
      for (int tt = 0; tt < 2; ++tt) {
        const float* pp = tt ? p1 : p0;
        unsigned wd[8];
#pragma unroll
        for (int j = 0; j < 8; ++j) wd[j] = cvt_pk_bf16(pp[2 * j], pp[2 * j + 1]);
        uv2 sA = __builtin_amdgcn_permlane32_swap(wd[0], wd[2], false, false);
        uv2 sB = __builtin_amdgcn_permlane32_swap(wd[1], wd[3], false, false);
        uv2 sC = __builtin_amdgcn_permlane32_swap(wd[4], wd[6], false, false);
        uv2 sD = __builtin_amdgcn_permlane32_swap(wd[5], wd[7], false, false);
        u32x4 f0 = {sA[0], sB[0], sA[1], sB[1]};
        u32x4 f1 = {sC[0], sD[0], sC[1], sD[1]};
        pf[tt * 2 + 0] = __builtin_bit_cast(bf16x8, f0);
        pf[tt * 2 + 1] = __builtin_bit_cast(bf16x8, f1);
      }

      // V(t) must have landed; K(t+1)'s 2 loads may stay in flight
      if (t + 1 < NT)
        asm volatile("s_waitcnt vmcnt(2)" ::: "memory");
      else
        asm volatile("s_waitcnt vmcnt(0)" ::: "memory");

      __builtin_amdgcn_s_setprio(1);
#pragma unroll
      for (int ks = 0; ks < 4; ++ks) {
        int c = (ks * 16 + hh * 8) ^ ksw;
        bf16x8 vf0 = *(const bf16x8*)&Vc[l31 * 64 + c];
        bf16x8 vf1 = *(const bf16x8*)&Vc[(32 + l31) * 64 + c];
        acc0 = __builtin_amdgcn_mfma_f32_32x32x16_bf16(vf0, pf[ks], acc0, 0, 0, 0);
        acc1 = __builtin_amdgcn_mfma_f32_32x32x16_bf16(vf1, pf[ks], acc1, 0, 0, 0);
      }
      __builtin_amdgcn_s_setprio(0);
    }

    asm volatile("" ::: "memory");
    cur ^= 1;
  }
#undef KSTAGE
#undef VSTAGE

  __syncthreads();  // all compute reads of smem done before merge reuse

  float* MRG = (float*)smem;
  float4* CH = (float4*)smem;
  if (half == 1) {
#pragma unroll
    for (int c = 0; c < 4; ++c) {
      float4 v0 = {acc0[4 * c + 0], acc0[4 * c + 1], acc0[4 * c + 2], acc0[4 * c + 3]};
      float4 v1 = {acc1[4 * c + 0], acc1[4 * c + 1], acc1[4 * c + 2], acc1[4 * c + 3]};
      CH[(wq4 * 8 + c) * 64 + lane] = v0;
      CH[(wq4 * 8 + 4 + c) * 64 + lane] = v1;
    }
    MRG[8192 + wq4 * 128 + lane * 2 + 0] = mrun;
    MRG[8192 + wq4 * 128 + lane * 2 + 1] = lrun;
  }
  __syncthreads();
  if (half == 0) {
    float m1 = MRG[8192 + wq4 * 128 + lane * 2 + 0];
    float l1 = MRG[8192 + wq4 * 128 + lane * 2 + 1];
    float m = fmaxf(mrun, m1);
    float f0 = fexp2(mrun - m), f1 = fexp2(m1 - m);
    float inv = 1.f / (lrun * f0 + l1 * f1);
    float a = f0 * inv, b = f1 * inv;
    size_t obase = (size_t)qg * 2048 + h * 64;
#pragma unroll
    for (int c = 0; c < 4; ++c) {
      float4 r0 = CH[(wq4 * 8 + c) * 64 + lane];
      float4 r1 = CH[(wq4 * 8 + 4 + c) * 64 + lane];
      u16x4 o0, o1;
      o0[0] = f2bf(acc0[4 * c + 0] * a + r0.x * b);
      o0[1] = f2bf(acc0[4 * c + 1] * a + r0.y * b);
      o0[2] = f2bf(acc0[4 * c + 2] * a + r0.z * b);
      o0[3] = f2bf(acc0[4 * c + 3] * a + r0.w * b);
      o1[0] = f2bf(acc1[4 * c + 0] * a + r1.x * b);
      o1[1] = f2bf(acc1[4 * c + 1] * a + r1.y * b);
      o1[2] = f2bf(acc1[4 * c + 2] * a + r1.z * b);
      o1[3] = f2bf(acc1[4 * c + 3] * a + r1.w * b);
      *(u16x4*)&attn_out[obase + 8 * c + 4 * hh] = o0;
      *(u16x4*)&attn_out[obase + 32 + 8 * c + 4 * hh] = o1;
    }
  }
}

extern "C" void kernel_launch(void* const* d_in, const int* in_sizes, int n_in,
                              void* d_out, int out_size, void* d_ws, size_t ws_size,
                              hipStream_t stream) {
  const float* x = (const float*)d_in[0];
  const float* fcos = (const float*)d_in[1];
  const float* fsin = (const float*)d_in[2];
  const float* wq = (const float*)d_in[4];
  const float* wk = (const float*)d_in[5];
  const float* wv = (const float*)d_in[6];
  const float* wo = (const float*)d_in[7];

  char* ws = (char*)d_ws;
  u16* xb    = (u16*)(ws);                    // 8 MB (reused as attn later)
  u16* wqkvT = (u16*)(ws + (8u << 20));       // 10 MB
  u16* woT   = (u16*)(ws + (18u << 20));      // 8 MB
  u16* QKV   = (u16*)(ws + (26u << 20));      // 10 MB
  u16* VT    = (u16*)(ws + (36u << 20));      // 1 MB
  u16* attn  = xb;

  prep_fused<<<11264, 256, 0, stream>>>(x, wq, wk, wv, wo, xb, wqkvT, woT);

  gemm_bt<false, true><<<dim3(20, 32), 512, 0, stream>>>(xb, wqkvT, QKV, 2048, 2560, 2048,
                                                         fcos, fsin, VT);

  attn_kernel<<<dim3(32, 16), 512, 0, stream>>>(QKV, VT, attn);

  gemm_bt<true, false><<<dim3(16, 32), 512, 0, stream>>>(attn, woT, d_out, 2048, 2048, 2048,
                                                         nullptr, nullptr, nullptr);
}

// Round 16
// 112.660 us; speedup vs baseline: 2.1754x; 1.0188x over previous
//
#include <hip/hip_runtime.h>

typedef unsigned short u16;
typedef __attribute__((ext_vector_type(4))) float f32x4;
typedef __attribute__((ext_vector_type(16))) float f32x16;
typedef __attribute__((ext_vector_type(8))) short bf16x8;
typedef __attribute__((ext_vector_type(4))) unsigned short u16x4;
typedef __attribute__((ext_vector_type(4))) unsigned u32x4;
typedef __attribute__((ext_vector_type(2))) unsigned uv2;

__device__ __forceinline__ u16 f2bf(float f) {
  unsigned u = __float_as_uint(f);
  u += 0x7FFFu + ((u >> 16) & 1u);
  return (u16)(u >> 16);
}
__device__ __forceinline__ float bf2f(u16 v) {
  return __uint_as_float(((unsigned)v) << 16);
}

__device__ __forceinline__ void gload_lds16(const u16* g, u16* l) {
  __builtin_amdgcn_global_load_lds((const __attribute__((address_space(1))) void*)g,
                                   (__attribute__((address_space(3))) void*)l, 16, 0, 0);
}

__device__ __forceinline__ unsigned cvt_pk_bf16(float lo, float hi) {
  unsigned r;
  asm("v_cvt_pk_bf16_f32 %0, %1, %2" : "=v"(r) : "v"(lo), "v"(hi));
  return r;
}

__device__ __forceinline__ float fexp2(float x) {
#if __has_builtin(__builtin_amdgcn_exp2f)
  return __builtin_amdgcn_exp2f(x);
#else
  return __expf(x * 0.6931471805599453f);
#endif
}

// ---------------- fused prep: x->bf16 + wq/wk/wv/wo transposes ----------------
__global__ __launch_bounds__(256) void prep_fused(const float* __restrict__ x,
                                                  const float* __restrict__ wq,
                                                  const float* __restrict__ wk,
                                                  const float* __restrict__ wv,
                                                  const float* __restrict__ wo,
                                                  u16* __restrict__ xb,
                                                  u16* __restrict__ wqkvT,
                                                  u16* __restrict__ woT) {
  const int b = blockIdx.x, tid = threadIdx.x;
  if (b < 2048) {
    int i = (b * 256 + tid) * 8;
    float4 v0 = *(const float4*)&x[i];
    float4 v1 = *(const float4*)&x[i + 4];
    u16x4 o0 = {f2bf(v0.x), f2bf(v0.y), f2bf(v0.z), f2bf(v0.w)};
    u16x4 o1 = {f2bf(v1.x), f2bf(v1.y), f2bf(v1.z), f2bf(v1.w)};
    *(u16x4*)&xb[i] = o0;
    *(u16x4*)&xb[i + 4] = o1;
    return;
  }
  __shared__ float tile[32][33];
  int tb = b - 2048;
  const float* src;
  u16* dst;
  int C, nbase, r0, c0;
  if (tb < 4096) {
    src = wq; dst = wqkvT; C = 2048;
    c0 = (tb >> 6) * 32; r0 = (tb & 63) * 32; nbase = c0;
  } else if (tb < 4608) {
    tb -= 4096; src = wk; dst = wqkvT; C = 256;
    c0 = (tb >> 6) * 32; r0 = (tb & 63) * 32; nbase = 2048 + c0;
  } else if (tb < 5120) {
    tb -= 4608; src = wv; dst = wqkvT; C = 256;
    c0 = (tb >> 6) * 32; r0 = (tb & 63) * 32; nbase = 2304 + c0;
  } else {
    tb -= 5120; src = wo; dst = woT; C = 2048;
    c0 = (tb >> 6) * 32; r0 = (tb & 63) * 32; nbase = c0;
  }
  {
    int tr = tid >> 3, tc4 = (tid & 7) << 2;
    float4 v = *(const float4*)&src[(size_t)(r0 + tr) * C + c0 + tc4];
    tile[tr][tc4 + 0] = v.x;
    tile[tr][tc4 + 1] = v.y;
    tile[tr][tc4 + 2] = v.z;
    tile[tr][tc4 + 3] = v.w;
  }
  __syncthreads();
  {
    int orow = tid >> 3, oc = (tid & 7) << 2;
    u16x4 o;
#pragma unroll
    for (int e = 0; e < 4; ++e) o[e] = f2bf(tile[oc + e][orow]);
    *(u16x4*)&dst[(size_t)(nbase + orow) * 2048 + r0 + oc] = o;
  }
}

// ---------------- GEMM v5: 64x128 tile, 8 waves, BK=64, dbuf, 1 barrier/iter ----------------
template <bool F32OUT, bool DO_ROPE>
__global__ __launch_bounds__(512, 6) void gemm_bt(const u16* __restrict__ A,
                                                  const u16* __restrict__ BT,
                                                  void* __restrict__ Cout,
                                                  int M, int N, int K,
                                                  const float* __restrict__ cosT,
                                                  const float* __restrict__ sinT,
                                                  u16* __restrict__ VTout) {
  const int bn = blockIdx.x * 128, bm = blockIdx.y * 64;
  const int tid = threadIdx.x;
  const int wid = tid >> 6, lane = tid & 63;
  const int wr = wid >> 2, wc = wid & 3;
  const int lrow = lane & 15, g = lane >> 4;

  __shared__ __align__(16) u16 As[2][64 * 64];
  __shared__ __align__(16) u16 Bs[2][128 * 64];

  const int srow = tid >> 3;
  const int cswz = (((tid & 7) ^ (srow & 7)) << 3);
  const u16* a_src = A + (size_t)(bm + srow) * K + cswz;
  const u16* b_src = BT + (size_t)(bn + srow) * K + cswz;

  const int swz16 = (lrow & 7) << 3;
  const int colsw0 = (g * 8) ^ swz16;
  const int colsw1 = (32 + g * 8) ^ swz16;

#define STAGE(buf, k0)                                                        \
  do {                                                                        \
    gload_lds16(a_src + (k0), &As[buf][0] + tid * 8);                         \
    gload_lds16(b_src + (k0), &Bs[buf][0] + tid * 8);                         \
    gload_lds16(b_src + (size_t)64 * K + (k0), &Bs[buf][0] + 4096 + tid * 8); \
  } while (0)

  f32x4 acc[2][2] = {};

  const int nt = K >> 6;
  STAGE(0, 0);
  int cur = 0;
  for (int t = 0; t < nt; ++t) {
    asm volatile("s_waitcnt vmcnt(0)" ::: "memory");
    __builtin_amdgcn_s_barrier();
    asm volatile("" ::: "memory");
    if (t + 1 < nt) STAGE(cur ^ 1, (t + 1) * 64);

    bf16x8 af[2][2], bfr[2][2];
#pragma unroll
    for (int m = 0; m < 2; ++m) {
      int row = wr * 32 + m * 16 + lrow;
      af[m][0] = *(const bf16x8*)&As[cur][row * 64 + colsw0];
      af[m][1] = *(const bf16x8*)&As[cur][row * 64 + colsw1];
    }
#pragma unroll
    for (int n = 0; n < 2; ++n) {
      int row = wc * 32 + n * 16 + lrow;
      bfr[n][0] = *(const bf16x8*)&Bs[cur][row * 64 + colsw0];
      bfr[n][1] = *(const bf16x8*)&Bs[cur][row * 64 + colsw1];
    }
#pragma unroll
    for (int ks = 0; ks < 2; ++ks)
#pragma unroll
      for (int m = 0; m < 2; ++m)
#pragma unroll
        for (int n = 0; n < 2; ++n)
          acc[m][n] =
              __builtin_amdgcn_mfma_f32_16x16x32_bf16(af[m][ks], bfr[n][ks], acc[m][n], 0, 0, 0);

    asm volatile("" ::: "memory");
    cur ^= 1;
  }
#undef STAGE

#pragma unroll
  for (int m = 0; m < 2; ++m) {
    int row0 = bm + wr * 32 + m * 16 + (g << 2);
#pragma unroll
    for (int n = 0; n < 2; ++n) {
      int col = bn + wc * 32 + n * 16 + lrow;
      f32x4 v = acc[m][n];
      if constexpr (DO_ROPE) {
        if (bn < 2304) {
          int i = (col & 63) >> 1;
          float sg = (col & 1) ? 1.f : -1.f;
#pragma unroll
          for (int r = 0; r < 4; ++r) {
            float pv = __shfl_xor(v[r], 1, 64);
            float c = cosT[(row0 + r) * 32 + i];
            float s = sinT[(row0 + r) * 32 + i];
            v[r] = v[r] * c + pv * s * sg;
          }
        } else {
          u16x4 o;
#pragma unroll
          for (int r = 0; r < 4; ++r) o[r] = f2bf(v[r]);
          *(u16x4*)&VTout[(size_t)(col - 2304) * 2048 + row0] = o;
          continue;
        }
      }
#pragma unroll
      for (int r = 0; r < 4; ++r) {
        if constexpr (F32OUT)
          ((float*)Cout)[(size_t)(row0 + r) * N + col] = v[r];
        else
          ((u16*)Cout)[(size_t)(row0 + r) * N + col] = f2bf(v[r]);
      }
    }
  }
}

// ---------------- flash attention v9 (R13 best): K+V dbuf, 64KB, 1 barrier/iter ----------------
__global__ __launch_bounds__(512) void attn_kernel(const u16* __restrict__ QKV,
                                                   const u16* __restrict__ VT,
                                                   u16* __restrict__ attn_out) {
  const int h = blockIdx.x;
  const int yy = (int)blockIdx.y;
  const int qb = (yy < 8) ? yy : 23 - yy;  // pair-sum = 15 per CU
  const int tid = threadIdx.x, w = tid >> 6, lane = tid & 63;
  const int wq4 = w & 3, half = w >> 2;
  const int l31 = lane & 31, hh = lane >> 5;
  const int kh = h >> 3;
  const int q0w = qb * 128 + wq4 * 32;
  const int qg = q0w + l31;

  __shared__ __align__(16) u16 smem[32768];

  const int srow8 = lane >> 3;
  const int scol = (((lane & 7) ^ srow8) << 3);

#define ASTAGE(buf, kb)                                                              \
  do {                                                                               \
    u16* kd = smem + (half * 2 + (buf)) * 4096 + (wq4 * 8) * 64 + lane * 8;          \
    u16* vd = smem + 16384 + (half * 2 + (buf)) * 4096 + (wq4 * 8) * 64 + lane * 8;  \
    _Pragma("unroll") for (int p = 0; p < 2; ++p) {                                  \
      int rr = p * 32 + wq4 * 8 + srow8;                                             \
      gload_lds16(QKV + (size_t)((kb) + rr) * 2560 + 2048 + kh * 64 + scol,          \
                  kd + p * 2048);                                                    \
      gload_lds16(VT + (size_t)(kh * 64 + rr) * 2048 + (kb) + scol, vd + p * 2048);  \
    }                                                                                \
  } while (0)

  bf16x8 qf[4];
  {
    size_t base = (size_t)qg * 2560 + h * 64 + hh * 8;
#pragma unroll
    for (int ks = 0; ks < 4; ++ks) qf[ks] = *(const bf16x8*)&QKV[base + ks * 16];
  }

  const int ksw = (l31 & 7) << 3;

  f32x16 acc0 = {}, acc1 = {};
  float mrun = -1e30f, lrun = 0.f;
  const float SC = 0.125f * 1.44269504088896f;

  const int NT = qb + 1;
  ASTAGE(0, half * 64);
  int cur = 0;

  for (int t = 0; t < NT; ++t) {
    const int kb = (2 * t + half) * 64;
    asm volatile("s_waitcnt vmcnt(0)" ::: "memory");
    __builtin_amdgcn_s_barrier();
    asm volatile("" ::: "memory");
    if (t + 1 < NT) ASTAGE(cur ^ 1, kb + 128);

    if (kb <= q0w + 31) {
      const u16* Kc = smem + (half * 2 + cur) * 4096;
      const u16* Vc = smem + 16384 + (half * 2 + cur) * 4096;

      f32x16 sc0 = {}, sc1 = {};
      __builtin_amdgcn_s_setprio(1);
#pragma unroll
      for (int ks = 0; ks < 4; ++ks) {
        int c = (ks * 16 + hh * 8) ^ ksw;
        bf16x8 kf0 = *(const bf16x8*)&Kc[l31 * 64 + c];
        bf16x8 kf1 = *(const bf16x8*)&Kc[(32 + l31) * 64 + c];
        sc0 = __builtin_amdgcn_mfma_f32_32x32x16_bf16(kf0, qf[ks], sc0, 0, 0, 0);
        sc1 = __builtin_amdgcn_mfma_f32_32x32x16_bf16(kf1, qf[ks], sc1, 0, 0, 0);
      }
      __builtin_amdgcn_s_setprio(0);

      if (kb + 63 > q0w) {
#pragma unroll
        for (int r = 0; r < 16; ++r) {
          int keyoff = (r & 3) + 8 * (r >> 2) + 4 * hh;
          if (kb + keyoff > qg) sc0[r] = -1e5f;
          if (kb + 32 + keyoff > qg) sc1[r] = -1e5f;
        }
      }

      float m8[8];
#pragma unroll
      for (int i = 0; i < 8; ++i)
        m8[i] = fmaxf(fmaxf(sc0[i], sc0[i + 8]), fmaxf(sc1[i], sc1[i + 8]));
#pragma unroll
      for (int st = 4; st >= 1; st >>= 1)
#pragma unroll
        for (int i = 0; i < st; ++i) m8[i] = fmaxf(m8[i], m8[i + st]);
      float mx = fmaxf(m8[0], __shfl_xor(m8[0], 32, 64));
      float mxs = mx * SC;

      if (__any(mxs > mrun + 8.f)) {
        float nm = fmaxf(mrun, mxs);
        float fs = fexp2(mrun - nm);
        mrun = nm;
        lrun *= fs;
#pragma unroll
        for (int i = 0; i < 16; ++i) { acc0[i] *= fs; acc1[i] *= fs; }
      }

      float p0[16], p1[16];
      const float nmn = -mrun;
#pragma unroll
      for (int i = 0; i < 16; ++i) {
        p0[i] = fexp2(__builtin_fmaf(sc0[i], SC, nmn));
        p1[i] = fexp2(__builtin_fmaf(sc1[i], SC, nmn));
      }
      float s8[8];
#pragma unroll
      for (int i = 0; i < 8; ++i) s8[i] = (p0[i] + p0[i + 8]) + (p1[i] + p1[i + 8]);
#pragma unroll
      for (int st = 4; st >= 1; st >>= 1)
#pragma unroll
        for (int i = 0; i < st; ++i) s8[i] += s8[i + st];
      lrun += s8[0] + __shfl_xor(s8[0], 32, 64);

      bf16x8 pf[4];
#pragma unroll
      for (int tt = 0; tt < 2; ++tt) {
        const float* pp = tt ? p1 : p0;
        unsigned wd[8];
#pragma unroll
        for (int j = 0; j < 8; ++j) wd[j] = cvt_pk_bf16(pp[2 * j], pp[2 * j + 1]);
        uv2 sA = __builtin_amdgcn_permlane32_swap(wd[0], wd[2], false, false);
        uv2 sB = __builtin_amdgcn_permlane32_swap(wd[1], wd[3], false, false);
        uv2 sC = __builtin_amdgcn_permlane32_swap(wd[4], wd[6], false, false);
        uv2 sD = __builtin_amdgcn_permlane32_swap(wd[5], wd[7], false, false);
        u32x4 f0 = {sA[0], sB[0], sA[1], sB[1]};
        u32x4 f1 = {sC[0], sD[0], sC[1], sD[1]};
        pf[tt * 2 + 0] = __builtin_bit_cast(bf16x8, f0);
        pf[tt * 2 + 1] = __builtin_bit_cast(bf16x8, f1);
      }

      __builtin_amdgcn_s_setprio(1);
#pragma unroll
      for (int ks = 0; ks < 4; ++ks) {
        int c = (ks * 16 + hh * 8) ^ ksw;
        bf16x8 vf0 = *(const bf16x8*)&Vc[l31 * 64 + c];
        bf16x8 vf1 = *(const bf16x8*)&Vc[(32 + l31) * 64 + c];
        acc0 = __builtin_amdgcn_mfma_f32_32x32x16_bf16(vf0, pf[ks], acc0, 0, 0, 0);
        acc1 = __builtin_amdgcn_mfma_f32_32x32x16_bf16(vf1, pf[ks], acc1, 0, 0, 0);
      }
      __builtin_amdgcn_s_setprio(0);
    }

    asm volatile("" ::: "memory");
    cur ^= 1;
  }
#undef ASTAGE

  __syncthreads();  // all compute reads of smem done before merge reuse

  float* MRG = (float*)smem;
  float4* CH = (float4*)smem;
  if (half == 1) {
#pragma unroll
    for (int c = 0; c < 4; ++c) {
      float4 v0 = {acc0[4 * c + 0], acc0[4 * c + 1], acc0[4 * c + 2], acc0[4 * c + 3]};
      float4 v1 = {acc1[4 * c + 0], acc1[4 * c + 1], acc1[4 * c + 2], acc1[4 * c + 3]};
      CH[(wq4 * 8 + c) * 64 + lane] = v0;
      CH[(wq4 * 8 + 4 + c) * 64 + lane] = v1;
    }
    MRG[8192 + wq4 * 128 + lane * 2 + 0] = mrun;
    MRG[8192 + wq4 * 128 + lane * 2 + 1] = lrun;
  }
  __syncthreads();
  if (half == 0) {
    float m1 = MRG[8192 + wq4 * 128 + lane * 2 + 0];
    float l1 = MRG[8192 + wq4 * 128 + lane * 2 + 1];
    float m = fmaxf(mrun, m1);
    float f0 = fexp2(mrun - m), f1 = fexp2(m1 - m);
    float inv = 1.f / (lrun * f0 + l1 * f1);
    float a = f0 * inv, b = f1 * inv;
    size_t obase = (size_t)qg * 2048 + h * 64;
#pragma unroll
    for (int c = 0; c < 4; ++c) {
      float4 r0 = CH[(wq4 * 8 + c) * 64 + lane];
      float4 r1 = CH[(wq4 * 8 + 4 + c) * 64 + lane];
      u16x4 o0, o1;
      o0[0] = f2bf(acc0[4 * c + 0] * a + r0.x * b);
      o0[1] = f2bf(acc0[4 * c + 1] * a + r0.y * b);
      o0[2] = f2bf(acc0[4 * c + 2] * a + r0.z * b);
      o0[3] = f2bf(acc0[4 * c + 3] * a + r0.w * b);
      o1[0] = f2bf(acc1[4 * c + 0] * a + r1.x * b);
      o1[1] = f2bf(acc1[4 * c + 1] * a + r1.y * b);
      o1[2] = f2bf(acc1[4 * c + 2] * a + r1.z * b);
      o1[3] = f2bf(acc1[4 * c + 3] * a + r1.w * b);
      *(u16x4*)&attn_out[obase + 8 * c + 4 * hh] = o0;
      *(u16x4*)&attn_out[obase + 32 + 8 * c + 4 * hh] = o1;
    }
  }
}

extern "C" void kernel_launch(void* const* d_in, const int* in_sizes, int n_in,
                              void* d_out, int out_size, void* d_ws, size_t ws_size,
                              hipStream_t stream) {
  const float* x = (const float*)d_in[0];
  const float* fcos = (const float*)d_in[1];
  const float* fsin = (const float*)d_in[2];
  const float* wq = (const float*)d_in[4];
  const float* wk = (const float*)d_in[5];
  const float* wv = (const float*)d_in[6];
  const float* wo = (const float*)d_in[7];

  char* ws = (char*)d_ws;
  u16* xb    = (u16*)(ws);                    // 8 MB (reused as attn later)
  u16* wqkvT = (u16*)(ws + (8u << 20));       // 10 MB
  u16* woT   = (u16*)(ws + (18u << 20));      // 8 MB
  u16* QKV   = (u16*)(ws + (26u << 20));      // 10 MB
  u16* VT    = (u16*)(ws + (36u << 20));      // 1 MB
  u16* attn  = xb;

  prep_fused<<<11264, 256, 0, stream>>>(x, wq, wk, wv, wo, xb, wqkvT, woT);

  gemm_bt<false, true><<<dim3(20, 32), 512, 0, stream>>>(xb, wqkvT, QKV, 2048, 2560, 2048,
                                                         fcos, fsin, VT);

  attn_kernel<<<dim3(32, 16), 512, 0, stream>>>(QKV, VT, attn);

  gemm_bt<true, false><<<dim3(16, 32), 512, 0, stream>>>(attn, woT, d_out, 2048, 2048, 2048,
                                                         nullptr, nullptr, nullptr);
}